// Round 9
// baseline (297.639 us; speedup 1.0000x reference)
//
#include <hip/hip_runtime.h>
#include <hip/hip_bf16.h>

#define NN 100000
#define NE 1600000
#define BNODES 196          // nodes per bucket
#define NB 511              // ceil(NN/BNODES)
#define NBLKA 256           // blocks in hist/scatter
#define CHUNK 6250          // NE / NBLKA, exact

typedef unsigned short u16;
typedef unsigned int u32;
using frag  = __attribute__((ext_vector_type(8))) short;   // 8 bf16 = 4 VGPR
using f32x4 = __attribute__((ext_vector_type(4))) float;   // MFMA C/D

// ---------------- workspace layout (byte offsets), total 60,637,184 B ----------------
#define OFF_CNT   (0)                 // NN int
#define OFF_OFFS  (512u << 10)        // NN int
#define OFF_BB    (1u << 20)          // NB+2 int
#define OFF_H     (1310720u)          // NBLKA*512 int = 512KB (dead after A3)
#define OFF_CSR   (2u << 20)          // NE int (+8 pad ints, zeroed)
#define OFF_WT1   (8704u << 10)       // 32KB bf16 packed
#define OFF_WT2   ((8704u << 10) + 65536u)
#define OFF_XB    (9u << 20)          // NN*128 bf16 = 25.6MB (becomes hb in-place)
#define OFF_AGGB  (35037184u)         // NN*128 bf16 = 25.6MB
#define OFF_REC   (54237184u)         // NE u32 = 6.4MB, overlaps aggb tail (dead by agg)

// round-to-nearest-even f32 -> bf16 bits
__device__ __forceinline__ u16 f2bf(float f) {
    u32 u = __float_as_uint(f);
    u32 r = u + 0x7fffu + ((u >> 16) & 1u);
    return (u16)(r >> 16);
}

// per-block int64/int32 detection
__device__ __forceinline__ bool edges_are_i64(const void* edges) {
    const long long* e = (const long long*)edges;
    bool ok = true;
#pragma unroll
    for (int i = 0; i < 4; i++) {
        long long v = e[i];
        if (v < 0 || v >= NN) ok = false;
    }
    return ok;
}

// A1: per-block LDS histogram over buckets (LDS int atomics only)
__global__ __launch_bounds__(256) void hist_kernel(const void* edges, int* H) {
    __shared__ int h[512];
    int tid = threadIdx.x, blk = blockIdx.x;
    for (int i = tid; i < 512; i += 256) h[i] = 0;
    __syncthreads();
    bool f = edges_are_i64(edges);
    int lo = blk * CHUNK, hi = lo + CHUNK;
    if (f) {
        const long long* dst = (const long long*)edges + NE;
        for (int i = lo + tid; i < hi; i += 256) atomicAdd(&h[(int)dst[i] / BNODES], 1);
    } else {
        const int* dst = (const int*)edges + NE;
        for (int i = lo + tid; i < hi; i += 256) atomicAdd(&h[dst[i] / BNODES], 1);
    }
    __syncthreads();
    for (int i = tid; i < 512; i += 256) H[blk * 512 + i] = h[i];
}

// A2: H[blk][b] -> exclusive prefix over blk, + bucket bases bb[]; rebase H to global indices
__global__ void scan_kernel(int* H, int* bb) {
    __shared__ int sc[512];
    int b = threadIdx.x;  // 512 threads
    int s = 0;
    for (int blk = 0; blk < NBLKA; blk++) {
        int v = H[blk * 512 + b];
        H[blk * 512 + b] = s;
        s += v;
    }
    sc[b] = s;
    __syncthreads();
    for (int off = 1; off < 512; off <<= 1) {
        int v = (b >= off) ? sc[b - off] : 0;
        __syncthreads();
        sc[b] += v;
        __syncthreads();
    }
    bb[b] = sc[b] - s;          // exclusive bucket base
    if (b == 511) bb[512] = sc[511];
    __syncthreads();
    int base = bb[b];
    for (int blk = 0; blk < NBLKA; blk++) H[blk * 512 + b] += base;
}

// A3: scatter packed records (dst_local<<17 | src) into exact per-(block,bucket) regions
__global__ __launch_bounds__(256) void scatter_kernel(const void* edges, const int* H, u32* rec) {
    __shared__ int cur[512];
    int tid = threadIdx.x, blk = blockIdx.x;
    for (int i = tid; i < 512; i += 256) cur[i] = H[blk * 512 + i];
    __syncthreads();
    bool f = edges_are_i64(edges);
    int lo = blk * CHUNK, hi = lo + CHUNK;
    if (f) {
        const long long* e = (const long long*)edges;
        for (int i = lo + tid; i < hi; i += 256) {
            int d = (int)e[NE + i], s = (int)e[i];
            int b = d / BNODES;
            int p = atomicAdd(&cur[b], 1);
            rec[p] = ((u32)(d - b * BNODES) << 17) | (u32)s;
        }
    } else {
        const int* e = (const int*)edges;
        for (int i = lo + tid; i < hi; i += 256) {
            int d = e[NE + i], s = e[i];
            int b = d / BNODES;
            int p = atomicAdd(&cur[b], 1);
            rec[p] = ((u32)(d - b * BNODES) << 17) | (u32)s;
        }
    }
}

// B: per-bucket: LDS hist -> prefix -> cnt/offsets (no global atomics) -> csr scatter
__global__ __launch_bounds__(256) void bucket_csr_kernel(const u32* rec, const int* bb,
                                                         int* cnt, int* offsets, int* csr) {
    __shared__ int hcnt[200], hpre[200], hcur[200];
    int b = blockIdx.x, tid = threadIdx.x;
    int base = bb[b], total = bb[b + 1] - base;
    if (b == NB - 1 && tid < 8) csr[NE + tid] = 0;   // zero-pad tail for agg's over-read
    for (int i = tid; i < BNODES; i += 256) hcnt[i] = 0;
    __syncthreads();
    for (int i = tid; i < total; i += 256) atomicAdd(&hcnt[rec[base + i] >> 17], 1);
    __syncthreads();
    if (tid < 64) {  // wave 0: exclusive prefix over 196 counters (49 lanes x 4)
        int l = tid;
        int s0 = 0, s1 = 0, s2 = 0, s3 = 0;
        if (l < 49) {
            s0 = hcnt[l * 4]; s1 = hcnt[l * 4 + 1]; s2 = hcnt[l * 4 + 2]; s3 = hcnt[l * 4 + 3];
        }
        int t0 = s0, t1 = t0 + s1, t2 = t1 + s2, t3 = t2 + s3;
        int sc = t3;
#pragma unroll
        for (int off = 1; off < 64; off <<= 1) {
            int v = __shfl_up(sc, off, 64);
            if (l >= off) sc += v;
        }
        int lbase = sc - t3;
        if (l < 49) {
            hpre[l * 4] = lbase;      hpre[l * 4 + 1] = lbase + t0;
            hpre[l * 4 + 2] = lbase + t1; hpre[l * 4 + 3] = lbase + t2;
        }
    }
    __syncthreads();
    int node0 = b * BNODES;
    for (int i = tid; i < BNODES; i += 256) {
        int n = node0 + i;
        if (n < NN) { cnt[n] = hcnt[i]; offsets[n] = base + hpre[i]; }
    }
    for (int i = tid; i < BNODES; i += 256) hcur[i] = hpre[i];
    __syncthreads();
    for (int i = tid; i < total; i += 256) {
        u32 r = rec[base + i];
        int p = atomicAdd(&hcur[r >> 17], 1);
        csr[base + p] = (int)(r & 0x1FFFFu);
    }
}

// both layers' weights in one launch
__global__ void wtprep_kernel(const float* Wl1, const float* Wr1,
                              const float* Wl2, const float* Wr2, u16* Wst1, u16* Wst2) {
    int gid = blockIdx.x * 256 + threadIdx.x;
    int idx = gid & (32 * 128 * 8 - 1);
    const float* Wl = (gid < 32768) ? Wl1 : Wl2;
    const float* Wr = (gid < 32768) ? Wr1 : Wr2;
    u16* Wst = (gid < 32768) ? Wst1 : Wst2;
    int kb = idx >> 10, col = (idx >> 3) & 127, i = idx & 7;
    int k = kb * 8 + i;
    float v = (k < 128) ? Wl[col * 128 + k] : Wr[col * 128 + (k - 128)];
    Wst[idx] = f2bf(v);
}

// f32 x -> bf16 xb, 8 elems/thread
__global__ void cvt_kernel(const float* x, u16* xb) {
    size_t base = ((size_t)blockIdx.x * 256 + threadIdx.x) * 8;
    if (base >= (size_t)NN * 128) return;
    float4 v0 = *(const float4*)(x + base);
    float4 v1 = *(const float4*)(x + base + 4);
    uint4 w;
    w.x = (u32)f2bf(v0.x) | ((u32)f2bf(v0.y) << 16);
    w.y = (u32)f2bf(v0.z) | ((u32)f2bf(v0.w) << 16);
    w.z = (u32)f2bf(v1.x) | ((u32)f2bf(v1.y) << 16);
    w.w = (u32)f2bf(v1.z) | ((u32)f2bf(v1.w) << 16);
    *(uint4*)(xb + base) = w;
}

// 4 nodes/wave, 16 lanes x 16B per row. ALL loads unconditional (batched issue);
// validity handled by fmaf mask. Over-reads of csr hit the next node's valid
// indices (or the zeroed tail pad), so gather addresses stay in-bounds.
__global__ __launch_bounds__(256) void agg_kernel(const u16* __restrict__ feat,
                                                  const int* __restrict__ csr,
                                                  const int* __restrict__ offsets,
                                                  const int* __restrict__ cnt,
                                                  u16* __restrict__ aggb) {
    int tid = threadIdx.x;
    int lane = tid & 63;
    int wv = tid >> 6;            // wave in block (4)
    int slot = lane >> 4;         // node slot 0..3
    int c16 = lane & 15;          // 16B chunk within row
    int node = blockIdx.x * 16 + wv * 4 + slot;
    bool valid = node < NN;
    int beg = valid ? offsets[node] : 0;
    int deg = valid ? cnt[node] : 0;

    // max deg across the wave's 4 slots (loop bound is wave-uniform)
    int md = deg;
    md = max(md, __shfl_xor(md, 16, 64));
    md = max(md, __shfl_xor(md, 32, 64));

    float acc[8];
#pragma unroll
    for (int q = 0; q < 8; q++) acc[q] = 0.f;

    for (int j = 0; j < md; j += 8) {
        int s[8];
#pragma unroll
        for (int k = 0; k < 8; k++) s[k] = csr[beg + j + k];
        uint4 v[8];
#pragma unroll
        for (int k = 0; k < 8; k++) v[k] = *(const uint4*)(feat + (size_t)s[k] * 128 + c16 * 8);
#pragma unroll
        for (int k = 0; k < 8; k++) {
            float m = (j + k < deg) ? 1.0f : 0.0f;
            acc[0] = fmaf(m, __uint_as_float(v[k].x << 16), acc[0]);
            acc[1] = fmaf(m, __uint_as_float(v[k].x & 0xffff0000u), acc[1]);
            acc[2] = fmaf(m, __uint_as_float(v[k].y << 16), acc[2]);
            acc[3] = fmaf(m, __uint_as_float(v[k].y & 0xffff0000u), acc[3]);
            acc[4] = fmaf(m, __uint_as_float(v[k].z << 16), acc[4]);
            acc[5] = fmaf(m, __uint_as_float(v[k].z & 0xffff0000u), acc[5]);
            acc[6] = fmaf(m, __uint_as_float(v[k].w << 16), acc[6]);
            acc[7] = fmaf(m, __uint_as_float(v[k].w & 0xffff0000u), acc[7]);
        }
    }

    if (valid) {
        float inv = (deg > 0) ? 1.0f / (float)deg : 0.0f;
        uint4 w;
        w.x = (u32)f2bf(acc[0] * inv) | ((u32)f2bf(acc[1] * inv) << 16);
        w.y = (u32)f2bf(acc[2] * inv) | ((u32)f2bf(acc[3] * inv) << 16);
        w.z = (u32)f2bf(acc[4] * inv) | ((u32)f2bf(acc[5] * inv) << 16);
        w.w = (u32)f2bf(acc[6] * inv) | ((u32)f2bf(acc[7] * inv) << 16);
        *(uint4*)(aggb + (size_t)node * 128 + c16 * 8) = w;
    }
}

// MFMA GEMM: out[n,o] = sum_k [A||B][n,k] * W[k,o] + bias[o], K=256.
__global__ __launch_bounds__(256) void lin_kernel(const u16* __restrict__ Abuf,
                                                  const u16* __restrict__ Bbuf,
                                                  const u16* __restrict__ Wst,
                                                  const float* __restrict__ bias,
                                                  float* outF, u16* outH, int relu) {
    __shared__ u16 As[128][136];   // +8 pad: rows 4 banks apart
    __shared__ u16 Ws[16384];      // [16 kb][128 col][8 k] bf16, chunk-local

    int tid = threadIdx.x;
    int lane = tid & 63;
    int wid = tid >> 6;
    int wr = wid >> 1, wc = wid & 1;
    int nb = blockIdx.x * 128;
    int l15 = lane & 15, l4 = lane >> 4;

    f32x4 acc[4][4];
#pragma unroll
    for (int i = 0; i < 4; i++)
#pragma unroll
        for (int j = 0; j < 4; j++) acc[i][j] = (f32x4){0.f, 0.f, 0.f, 0.f};

    for (int c = 0; c < 2; c++) {
        const u16* Base = c ? Bbuf : Abuf;
        __syncthreads();

#pragma unroll
        for (int it = 0; it < 8; it++) {
            int idx = it * 256 + tid;
            int row = idx >> 4, c16 = idx & 15;
            float4 v = make_float4(0.f, 0.f, 0.f, 0.f);
            if (nb + row < NN)
                v = *(const float4*)(Base + (size_t)(nb + row) * 128 + c16 * 8);
            *(float4*)&As[row][c16 * 8] = v;
        }
        const u16* wsrc = Wst + c * 16384;
#pragma unroll
        for (int it = 0; it < 8; it++) {
            int idx = it * 256 + tid;
            *(float4*)&Ws[idx * 8] = *(const float4*)(wsrc + idx * 8);
        }
        __syncthreads();

#pragma unroll
        for (int kk = 0; kk < 4; kk++) {
            frag a[4], bfr[4];
#pragma unroll
            for (int i = 0; i < 4; i++)
                a[i] = *(const frag*)&As[wr * 64 + i * 16 + l15][kk * 32 + l4 * 8];
#pragma unroll
            for (int j = 0; j < 4; j++)
                bfr[j] = *(const frag*)&Ws[((kk * 4 + l4) * 128 + wc * 64 + j * 16 + l15) * 8];
#pragma unroll
            for (int i = 0; i < 4; i++)
#pragma unroll
                for (int j = 0; j < 4; j++)
                    acc[i][j] = __builtin_amdgcn_mfma_f32_16x16x32_bf16(a[i], bfr[j], acc[i][j], 0, 0, 0);
        }
    }

    // epilogue: C/D layout col = lane&15, row = (lane>>4)*4 + reg
#pragma unroll
    for (int j = 0; j < 4; j++) {
        int col = wc * 64 + j * 16 + l15;
        float bv = bias[col];
#pragma unroll
        for (int i = 0; i < 4; i++) {
#pragma unroll
            for (int r = 0; r < 4; r++) {
                int node = nb + wr * 64 + i * 16 + l4 * 4 + r;
                if (node >= NN) continue;
                float v = acc[i][j][r] + bv;
                if (relu) {
                    v = fmaxf(v, 0.f);
                    outH[(size_t)node * 128 + col] = f2bf(v);
                } else {
                    outF[(size_t)node * 128 + col] = v;
                }
            }
        }
    }
}

extern "C" void kernel_launch(void* const* d_in, const int* in_sizes, int n_in,
                              void* d_out, int out_size, void* d_ws, size_t ws_size,
                              hipStream_t stream) {
    const float* x    = (const float*)d_in[0];
    const void* edges = d_in[1];
    const float* Wl1  = (const float*)d_in[2];
    const float* Wr1  = (const float*)d_in[3];
    const float* b1   = (const float*)d_in[4];
    const float* Wl2  = (const float*)d_in[5];
    const float* Wr2  = (const float*)d_in[6];
    const float* b2   = (const float*)d_in[7];
    float* out = (float*)d_out;

    char* ws = (char*)d_ws;
    int* cnt     = (int*)(ws + OFF_CNT);
    int* offsets = (int*)(ws + OFF_OFFS);
    int* bb      = (int*)(ws + OFF_BB);
    int* H       = (int*)(ws + OFF_H);
    int* csr     = (int*)(ws + OFF_CSR);
    u16* Wst1    = (u16*)(ws + OFF_WT1);
    u16* Wst2    = (u16*)(ws + OFF_WT2);
    u16* xb      = (u16*)(ws + OFF_XB);    // becomes hb after lin1 (in-place)
    u16* aggb    = (u16*)(ws + OFF_AGGB);
    u32* rec     = (u32*)(ws + OFF_REC);   // overlaps aggb tail; dead before agg1

    // CSR build: zero global atomics
    hist_kernel<<<NBLKA, 256, 0, stream>>>(edges, H);
    scan_kernel<<<1, 512, 0, stream>>>(H, bb);
    scatter_kernel<<<NBLKA, 256, 0, stream>>>(edges, H, rec);
    bucket_csr_kernel<<<NB, 256, 0, stream>>>(rec, bb, cnt, offsets, csr);

    wtprep_kernel<<<256, 256, 0, stream>>>(Wl1, Wr1, Wl2, Wr2, Wst1, Wst2);
    cvt_kernel<<<6250, 256, 0, stream>>>(x, xb);

    int lgrid = (NN + 127) / 128;  // 782
    int agrid = (NN + 15) / 16;    // 6250

    // layer 1: agg1 = mean-gather(xb); h = relu(lin(agg1, xb)) -> bf16 in-place into xb
    agg_kernel<<<agrid, 256, 0, stream>>>(xb, csr, offsets, cnt, aggb);
    lin_kernel<<<lgrid, 256, 0, stream>>>(aggb, xb, Wst1, b1, nullptr, xb, 1);

    // layer 2: agg2 = mean-gather(hb); out = lin(agg2, hb) -> f32 d_out
    agg_kernel<<<agrid, 256, 0, stream>>>(xb, csr, offsets, cnt, aggb);
    lin_kernel<<<lgrid, 256, 0, stream>>>(aggb, xb, Wst2, b2, out, nullptr, 0);
}

// Round 10
// 289.506 us; speedup vs baseline: 1.0281x; 1.0281x over previous
//
#include <hip/hip_runtime.h>
#include <hip/hip_bf16.h>

#define NN 100000
#define NE 1600000
#define BNODES 196          // nodes per bucket
#define NB 511              // ceil(NN/BNODES); hist/scan arrays padded to 512
#define NBLKA 256           // blocks in hist/scatter
#define CHUNK 6250          // NE / NBLKA, exact

typedef unsigned short u16;
typedef unsigned int u32;
using frag  = __attribute__((ext_vector_type(8))) short;   // 8 bf16 = 4 VGPR
using f32x4 = __attribute__((ext_vector_type(4))) float;   // MFMA C/D

// ---------------- workspace layout (byte offsets), total 60,637,184 B ----------------
#define OFF_CNT   (0)                 // NN int
#define OFF_OFFS  (512u << 10)        // NN int
#define OFF_BB    (1u << 20)          // 513 int (bucket bases)
#define OFF_BSUM  ((1u << 20) + 4096) // 512 int
#define OFF_H     (1310720u)          // NBLKA*512 int = 512KB (dead after A3)
#define OFF_CSR   (2u << 20)          // NE int (+8 pad ints, zeroed)
#define OFF_WT1   (8704u << 10)       // 32KB bf16 packed
#define OFF_WT2   ((8704u << 10) + 65536u)
#define OFF_XB    (9u << 20)          // NN*128 bf16 = 25.6MB (becomes hb in-place)
#define OFF_AGGB  (35037184u)         // NN*128 bf16 = 25.6MB
#define OFF_REC   (54237184u)         // NE u32 = 6.4MB, overlaps aggb tail (dead by agg)

// round-to-nearest-even f32 -> bf16 bits
__device__ __forceinline__ u16 f2bf(float f) {
    u32 u = __float_as_uint(f);
    u32 r = u + 0x7fffu + ((u >> 16) & 1u);
    return (u16)(r >> 16);
}

// per-block int64/int32 detection
__device__ __forceinline__ bool edges_are_i64(const void* edges) {
    const long long* e = (const long long*)edges;
    bool ok = true;
#pragma unroll
    for (int i = 0; i < 4; i++) {
        long long v = e[i];
        if (v < 0 || v >= NN) ok = false;
    }
    return ok;
}

// A1: per-block LDS histogram over buckets (LDS int atomics only)
__global__ __launch_bounds__(256) void hist_kernel(const void* edges, int* H) {
    __shared__ int h[512];
    int tid = threadIdx.x, blk = blockIdx.x;
    for (int i = tid; i < 512; i += 256) h[i] = 0;
    __syncthreads();
    bool f = edges_are_i64(edges);
    int lo = blk * CHUNK, hi = lo + CHUNK;
    if (f) {
        const long long* dst = (const long long*)edges + NE;
        for (int i = lo + tid; i < hi; i += 256)
            atomicAdd(&h[(int)__builtin_nontemporal_load(&dst[i]) / BNODES], 1);
    } else {
        const int* dst = (const int*)edges + NE;
        for (int i = lo + tid; i < hi; i += 256)
            atomicAdd(&h[__builtin_nontemporal_load(&dst[i]) / BNODES], 1);
    }
    __syncthreads();
    for (int i = tid; i < 512; i += 256) H[blk * 512 + i] = h[i];
}

// A2a: wave-per-bucket exclusive scan over 256 block entries (column of H);
// bsum[b] = column total. Grid 128 x 256 (4 waves = 4 buckets per block).
__global__ __launch_bounds__(256) void scan1_kernel(int* H, int* bsum) {
    int tid = threadIdx.x;
    int lane = tid & 63;
    int b = blockIdx.x * 4 + (tid >> 6);
    int v0 = H[(lane * 4 + 0) * 512 + b];
    int v1 = H[(lane * 4 + 1) * 512 + b];
    int v2 = H[(lane * 4 + 2) * 512 + b];
    int v3 = H[(lane * 4 + 3) * 512 + b];
    int t = v0 + v1 + v2 + v3;
    int sc = t;
#pragma unroll
    for (int off = 1; off < 64; off <<= 1) {
        int v = __shfl_up(sc, off, 64);
        if (lane >= off) sc += v;
    }
    int excl = sc - t;
    H[(lane * 4 + 0) * 512 + b] = excl;
    H[(lane * 4 + 1) * 512 + b] = excl + v0;
    H[(lane * 4 + 2) * 512 + b] = excl + v0 + v1;
    H[(lane * 4 + 3) * 512 + b] = excl + v0 + v1 + v2;
    if (lane == 63) bsum[b] = sc;
}

// A2b: exclusive prefix over 512 bucket totals -> bb[0..511], bb[512] = NE
__global__ void bb2_kernel(const int* bsum, int* bb) {
    __shared__ int sc[512];
    int b = threadIdx.x;  // 512 threads
    int s = bsum[b];
    sc[b] = s;
    __syncthreads();
    for (int off = 1; off < 512; off <<= 1) {
        int v = (b >= off) ? sc[b - off] : 0;
        __syncthreads();
        sc[b] += v;
        __syncthreads();
    }
    bb[b] = sc[b] - s;
    if (b == 511) bb[512] = sc[511];
}

// A3: scatter packed records (dst_local<<17 | src); base = bb[b] + local prefix
__global__ __launch_bounds__(256) void scatter_kernel(const void* edges, const int* H,
                                                      const int* bb, u32* rec) {
    __shared__ int cur[512];
    int tid = threadIdx.x, blk = blockIdx.x;
    for (int i = tid; i < 512; i += 256) cur[i] = bb[i] + H[blk * 512 + i];
    __syncthreads();
    bool f = edges_are_i64(edges);
    int lo = blk * CHUNK, hi = lo + CHUNK;
    if (f) {
        const long long* e = (const long long*)edges;
        for (int i = lo + tid; i < hi; i += 256) {
            int d = (int)__builtin_nontemporal_load(&e[NE + i]);
            int s = (int)__builtin_nontemporal_load(&e[i]);
            int b = d / BNODES;
            int p = atomicAdd(&cur[b], 1);
            rec[p] = ((u32)(d - b * BNODES) << 17) | (u32)s;
        }
    } else {
        const int* e = (const int*)edges;
        for (int i = lo + tid; i < hi; i += 256) {
            int d = __builtin_nontemporal_load(&e[NE + i]);
            int s = __builtin_nontemporal_load(&e[i]);
            int b = d / BNODES;
            int p = atomicAdd(&cur[b], 1);
            rec[p] = ((u32)(d - b * BNODES) << 17) | (u32)s;
        }
    }
}

// B: per-bucket: LDS hist -> prefix -> cnt/offsets (no global atomics) -> csr scatter
__global__ __launch_bounds__(256) void bucket_csr_kernel(const u32* rec, const int* bb,
                                                         int* cnt, int* offsets, int* csr) {
    __shared__ int hcnt[200], hpre[200], hcur[200];
    int b = blockIdx.x, tid = threadIdx.x;
    int base = bb[b], total = bb[b + 1] - base;
    if (b == NB - 1 && tid < 8) csr[NE + tid] = 0;   // zero-pad tail for agg's over-read
    for (int i = tid; i < BNODES; i += 256) hcnt[i] = 0;
    __syncthreads();
    for (int i = tid; i < total; i += 256)
        atomicAdd(&hcnt[__builtin_nontemporal_load(&rec[base + i]) >> 17], 1);
    __syncthreads();
    if (tid < 64) {  // wave 0: exclusive prefix over 196 counters (49 lanes x 4)
        int l = tid;
        int s0 = 0, s1 = 0, s2 = 0, s3 = 0;
        if (l < 49) {
            s0 = hcnt[l * 4]; s1 = hcnt[l * 4 + 1]; s2 = hcnt[l * 4 + 2]; s3 = hcnt[l * 4 + 3];
        }
        int t0 = s0, t1 = t0 + s1, t2 = t1 + s2, t3 = t2 + s3;
        int sc = t3;
#pragma unroll
        for (int off = 1; off < 64; off <<= 1) {
            int v = __shfl_up(sc, off, 64);
            if (l >= off) sc += v;
        }
        int lbase = sc - t3;
        if (l < 49) {
            hpre[l * 4] = lbase;      hpre[l * 4 + 1] = lbase + t0;
            hpre[l * 4 + 2] = lbase + t1; hpre[l * 4 + 3] = lbase + t2;
        }
    }
    __syncthreads();
    int node0 = b * BNODES;
    for (int i = tid; i < BNODES; i += 256) {
        int n = node0 + i;
        if (n < NN) { cnt[n] = hcnt[i]; offsets[n] = base + hpre[i]; }
    }
    for (int i = tid; i < BNODES; i += 256) hcur[i] = hpre[i];
    __syncthreads();
    for (int i = tid; i < total; i += 256) {
        u32 r = __builtin_nontemporal_load(&rec[base + i]);
        int p = atomicAdd(&hcur[r >> 17], 1);
        csr[base + p] = (int)(r & 0x1FFFFu);
    }
}

// both layers' weights in one launch
__global__ void wtprep_kernel(const float* Wl1, const float* Wr1,
                              const float* Wl2, const float* Wr2, u16* Wst1, u16* Wst2) {
    int gid = blockIdx.x * 256 + threadIdx.x;
    int idx = gid & (32 * 128 * 8 - 1);
    const float* Wl = (gid < 32768) ? Wl1 : Wl2;
    const float* Wr = (gid < 32768) ? Wr1 : Wr2;
    u16* Wst = (gid < 32768) ? Wst1 : Wst2;
    int kb = idx >> 10, col = (idx >> 3) & 127, i = idx & 7;
    int k = kb * 8 + i;
    float v = (k < 128) ? Wl[col * 128 + k] : Wr[col * 128 + (k - 128)];
    Wst[idx] = f2bf(v);
}

// f32 x -> bf16 xb, 8 elems/thread
__global__ void cvt_kernel(const float* x, u16* xb) {
    size_t base = ((size_t)blockIdx.x * 256 + threadIdx.x) * 8;
    if (base >= (size_t)NN * 128) return;
    float4 v0 = *(const float4*)(x + base);
    float4 v1 = *(const float4*)(x + base + 4);
    uint4 w;
    w.x = (u32)f2bf(v0.x) | ((u32)f2bf(v0.y) << 16);
    w.y = (u32)f2bf(v0.z) | ((u32)f2bf(v0.w) << 16);
    w.z = (u32)f2bf(v1.x) | ((u32)f2bf(v1.y) << 16);
    w.w = (u32)f2bf(v1.z) | ((u32)f2bf(v1.w) << 16);
    *(uint4*)(xb + base) = w;
}

// 4 nodes/wave, 16 lanes x 16B per row. ALL loads unconditional (batched issue);
// validity handled by fmaf mask. csr loads are nontemporal (streamed once) so
// they don't evict feat rows from L2.
__global__ __launch_bounds__(256) void agg_kernel(const u16* __restrict__ feat,
                                                  const int* __restrict__ csr,
                                                  const int* __restrict__ offsets,
                                                  const int* __restrict__ cnt,
                                                  u16* __restrict__ aggb) {
    int tid = threadIdx.x;
    int lane = tid & 63;
    int wv = tid >> 6;            // wave in block (4)
    int slot = lane >> 4;         // node slot 0..3
    int c16 = lane & 15;          // 16B chunk within row
    int node = blockIdx.x * 16 + wv * 4 + slot;
    bool valid = node < NN;
    int beg = valid ? offsets[node] : 0;
    int deg = valid ? cnt[node] : 0;

    // max deg across the wave's 4 slots (loop bound is wave-uniform)
    int md = deg;
    md = max(md, __shfl_xor(md, 16, 64));
    md = max(md, __shfl_xor(md, 32, 64));

    float acc[8];
#pragma unroll
    for (int q = 0; q < 8; q++) acc[q] = 0.f;

    for (int j = 0; j < md; j += 8) {
        int s[8];
#pragma unroll
        for (int k = 0; k < 8; k++) s[k] = __builtin_nontemporal_load(&csr[beg + j + k]);
        uint4 v[8];
#pragma unroll
        for (int k = 0; k < 8; k++) v[k] = *(const uint4*)(feat + (size_t)s[k] * 128 + c16 * 8);
#pragma unroll
        for (int k = 0; k < 8; k++) {
            float m = (j + k < deg) ? 1.0f : 0.0f;
            acc[0] = fmaf(m, __uint_as_float(v[k].x << 16), acc[0]);
            acc[1] = fmaf(m, __uint_as_float(v[k].x & 0xffff0000u), acc[1]);
            acc[2] = fmaf(m, __uint_as_float(v[k].y << 16), acc[2]);
            acc[3] = fmaf(m, __uint_as_float(v[k].y & 0xffff0000u), acc[3]);
            acc[4] = fmaf(m, __uint_as_float(v[k].z << 16), acc[4]);
            acc[5] = fmaf(m, __uint_as_float(v[k].z & 0xffff0000u), acc[5]);
            acc[6] = fmaf(m, __uint_as_float(v[k].w << 16), acc[6]);
            acc[7] = fmaf(m, __uint_as_float(v[k].w & 0xffff0000u), acc[7]);
        }
    }

    if (valid) {
        float inv = (deg > 0) ? 1.0f / (float)deg : 0.0f;
        uint4 w;
        w.x = (u32)f2bf(acc[0] * inv) | ((u32)f2bf(acc[1] * inv) << 16);
        w.y = (u32)f2bf(acc[2] * inv) | ((u32)f2bf(acc[3] * inv) << 16);
        w.z = (u32)f2bf(acc[4] * inv) | ((u32)f2bf(acc[5] * inv) << 16);
        w.w = (u32)f2bf(acc[6] * inv) | ((u32)f2bf(acc[7] * inv) << 16);
        *(uint4*)(aggb + (size_t)node * 128 + c16 * 8) = w;
    }
}

// MFMA GEMM: out[n,o] = sum_k [A||B][n,k] * W[k,o] + bias[o], K=256.
__global__ __launch_bounds__(256) void lin_kernel(const u16* __restrict__ Abuf,
                                                  const u16* __restrict__ Bbuf,
                                                  const u16* __restrict__ Wst,
                                                  const float* __restrict__ bias,
                                                  float* outF, u16* outH, int relu) {
    __shared__ u16 As[128][136];   // +8 pad: rows 4 banks apart
    __shared__ u16 Ws[16384];      // [16 kb][128 col][8 k] bf16, chunk-local

    int tid = threadIdx.x;
    int lane = tid & 63;
    int wid = tid >> 6;
    int wr = wid >> 1, wc = wid & 1;
    int nb = blockIdx.x * 128;
    int l15 = lane & 15, l4 = lane >> 4;

    f32x4 acc[4][4];
#pragma unroll
    for (int i = 0; i < 4; i++)
#pragma unroll
        for (int j = 0; j < 4; j++) acc[i][j] = (f32x4){0.f, 0.f, 0.f, 0.f};

    for (int c = 0; c < 2; c++) {
        const u16* Base = c ? Bbuf : Abuf;
        __syncthreads();

#pragma unroll
        for (int it = 0; it < 8; it++) {
            int idx = it * 256 + tid;
            int row = idx >> 4, c16 = idx & 15;
            float4 v = make_float4(0.f, 0.f, 0.f, 0.f);
            if (nb + row < NN)
                v = *(const float4*)(Base + (size_t)(nb + row) * 128 + c16 * 8);
            *(float4*)&As[row][c16 * 8] = v;
        }
        const u16* wsrc = Wst + c * 16384;
#pragma unroll
        for (int it = 0; it < 8; it++) {
            int idx = it * 256 + tid;
            *(float4*)&Ws[idx * 8] = *(const float4*)(wsrc + idx * 8);
        }
        __syncthreads();

#pragma unroll
        for (int kk = 0; kk < 4; kk++) {
            frag a[4], bfr[4];
#pragma unroll
            for (int i = 0; i < 4; i++)
                a[i] = *(const frag*)&As[wr * 64 + i * 16 + l15][kk * 32 + l4 * 8];
#pragma unroll
            for (int j = 0; j < 4; j++)
                bfr[j] = *(const frag*)&Ws[((kk * 4 + l4) * 128 + wc * 64 + j * 16 + l15) * 8];
#pragma unroll
            for (int i = 0; i < 4; i++)
#pragma unroll
                for (int j = 0; j < 4; j++)
                    acc[i][j] = __builtin_amdgcn_mfma_f32_16x16x32_bf16(a[i], bfr[j], acc[i][j], 0, 0, 0);
        }
    }

    // epilogue: C/D layout col = lane&15, row = (lane>>4)*4 + reg
#pragma unroll
    for (int j = 0; j < 4; j++) {
        int col = wc * 64 + j * 16 + l15;
        float bv = bias[col];
#pragma unroll
        for (int i = 0; i < 4; i++) {
#pragma unroll
            for (int r = 0; r < 4; r++) {
                int node = nb + wr * 64 + i * 16 + l4 * 4 + r;
                if (node >= NN) continue;
                float v = acc[i][j][r] + bv;
                if (relu) {
                    v = fmaxf(v, 0.f);
                    outH[(size_t)node * 128 + col] = f2bf(v);
                } else {
                    outF[(size_t)node * 128 + col] = v;
                }
            }
        }
    }
}

extern "C" void kernel_launch(void* const* d_in, const int* in_sizes, int n_in,
                              void* d_out, int out_size, void* d_ws, size_t ws_size,
                              hipStream_t stream) {
    const float* x    = (const float*)d_in[0];
    const void* edges = d_in[1];
    const float* Wl1  = (const float*)d_in[2];
    const float* Wr1  = (const float*)d_in[3];
    const float* b1   = (const float*)d_in[4];
    const float* Wl2  = (const float*)d_in[5];
    const float* Wr2  = (const float*)d_in[6];
    const float* b2   = (const float*)d_in[7];
    float* out = (float*)d_out;

    char* ws = (char*)d_ws;
    int* cnt     = (int*)(ws + OFF_CNT);
    int* offsets = (int*)(ws + OFF_OFFS);
    int* bb      = (int*)(ws + OFF_BB);
    int* bsum    = (int*)(ws + OFF_BSUM);
    int* H       = (int*)(ws + OFF_H);
    int* csr     = (int*)(ws + OFF_CSR);
    u16* Wst1    = (u16*)(ws + OFF_WT1);
    u16* Wst2    = (u16*)(ws + OFF_WT2);
    u16* xb      = (u16*)(ws + OFF_XB);    // becomes hb after lin1 (in-place)
    u16* aggb    = (u16*)(ws + OFF_AGGB);
    u32* rec     = (u32*)(ws + OFF_REC);   // overlaps aggb tail; dead before agg1

    // CSR build: zero global atomics, fully parallel scan
    hist_kernel<<<NBLKA, 256, 0, stream>>>(edges, H);
    scan1_kernel<<<128, 256, 0, stream>>>(H, bsum);
    bb2_kernel<<<1, 512, 0, stream>>>(bsum, bb);
    scatter_kernel<<<NBLKA, 256, 0, stream>>>(edges, H, bb, rec);
    bucket_csr_kernel<<<NB, 256, 0, stream>>>(rec, bb, cnt, offsets, csr);

    wtprep_kernel<<<256, 256, 0, stream>>>(Wl1, Wr1, Wl2, Wr2, Wst1, Wst2);
    cvt_kernel<<<6250, 256, 0, stream>>>(x, xb);

    int lgrid = (NN + 127) / 128;  // 782
    int agrid = (NN + 15) / 16;    // 6250

    // layer 1: agg1 = mean-gather(xb); h = relu(lin(agg1, xb)) -> bf16 in-place into xb
    agg_kernel<<<agrid, 256, 0, stream>>>(xb, csr, offsets, cnt, aggb);
    lin_kernel<<<lgrid, 256, 0, stream>>>(aggb, xb, Wst1, b1, nullptr, xb, 1);

    // layer 2: agg2 = mean-gather(hb); out = lin(agg2, hb) -> f32 d_out
    agg_kernel<<<agrid, 256, 0, stream>>>(xb, csr, offsets, cnt, aggb);
    lin_kernel<<<lgrid, 256, 0, stream>>>(aggb, xb, Wst2, b2, out, nullptr, 0);
}

// Round 11
// 266.982 us; speedup vs baseline: 1.1148x; 1.0844x over previous
//
#include <hip/hip_runtime.h>
#include <hip/hip_bf16.h>

#define NN 100000
#define NE 1600000
#define BNODES 196          // nodes per bucket
#define NB 511              // ceil(NN/BNODES); hist/scan arrays padded to 512
#define NBLKA 256           // blocks in hist/scatter
#define CHUNK 6250          // NE / NBLKA, exact

typedef unsigned short u16;
typedef unsigned int u32;
using frag  = __attribute__((ext_vector_type(8))) short;   // 8 bf16 = 4 VGPR
using f32x4 = __attribute__((ext_vector_type(4))) float;   // MFMA C/D

// ---------------- workspace layout (byte offsets), total 60,637,184 B ----------------
#define OFF_CNT   (0)                 // NN int
#define OFF_OFFS  (512u << 10)        // NN int
#define OFF_BB    (1u << 20)          // 513 int (bucket bases)
#define OFF_BSUM  ((1u << 20) + 4096) // 512 int
#define OFF_H     (1310720u)          // NBLKA*512 int = 512KB (dead after A3)
#define OFF_CSR   (2u << 20)          // NE int (+8 pad ints, zeroed)
#define OFF_WT1   (8704u << 10)       // 32KB bf16 packed
#define OFF_WT2   ((8704u << 10) + 65536u)
#define OFF_XB    (9u << 20)          // NN*128 bf16 = 25.6MB
#define OFF_HB    (35037184u)         // NN*128 bf16 = 25.6MB (layer-1 output)
#define OFF_REC   (54237184u)         // NE u32 = 6.4MB, overlaps HB tail (dead before fused1)

// round-to-nearest-even f32 -> bf16 bits
__device__ __forceinline__ u16 f2bf(float f) {
    u32 u = __float_as_uint(f);
    u32 r = u + 0x7fffu + ((u >> 16) & 1u);
    return (u16)(r >> 16);
}

// per-block int64/int32 detection
__device__ __forceinline__ bool edges_are_i64(const void* edges) {
    const long long* e = (const long long*)edges;
    bool ok = true;
#pragma unroll
    for (int i = 0; i < 4; i++) {
        long long v = e[i];
        if (v < 0 || v >= NN) ok = false;
    }
    return ok;
}

// A1: per-block LDS histogram over buckets + (folded) cvt slice + wtprep slice.
// cvt/wtprep are independent streams that fill hist's atomic-latency bubbles.
__global__ __launch_bounds__(256) void hist_kernel(const void* edges, int* H,
                                                   const float* x, u16* xb,
                                                   const float* Wl1, const float* Wr1,
                                                   const float* Wl2, const float* Wr2,
                                                   u16* Wst1, u16* Wst2) {
    __shared__ int h[512];
    int tid = threadIdx.x, blk = blockIdx.x;
    for (int i = tid; i < 512; i += 256) h[i] = 0;
    __syncthreads();

    // folded wtprep: 65536 bf16 total, 256 per block
    {
        int gid = blk * 256 + tid;
        int idx = gid & 32767;
        const float* Wl = (gid < 32768) ? Wl1 : Wl2;
        const float* Wr = (gid < 32768) ? Wr1 : Wr2;
        u16* Wst = (gid < 32768) ? Wst1 : Wst2;
        int kb = idx >> 10, col = (idx >> 3) & 127, i = idx & 7;
        int k = kb * 8 + i;
        float v = (k < 128) ? Wl[col * 128 + k] : Wr[col * 128 + (k - 128)];
        Wst[idx] = f2bf(v);
    }
    // folded cvt: 1.6M units of 8 elems; 6250 units per block
    {
        int u0 = blk * 6250;
        for (int u = u0 + tid; u < u0 + 6250; u += 256) {
            size_t base = (size_t)u * 8;
            float4 v0 = *(const float4*)(x + base);
            float4 v1 = *(const float4*)(x + base + 4);
            uint4 w;
            w.x = (u32)f2bf(v0.x) | ((u32)f2bf(v0.y) << 16);
            w.y = (u32)f2bf(v0.z) | ((u32)f2bf(v0.w) << 16);
            w.z = (u32)f2bf(v1.x) | ((u32)f2bf(v1.y) << 16);
            w.w = (u32)f2bf(v1.z) | ((u32)f2bf(v1.w) << 16);
            *(uint4*)(xb + base) = w;
        }
    }
    // histogram
    bool f = edges_are_i64(edges);
    int lo = blk * CHUNK, hi = lo + CHUNK;
    if (f) {
        const long long* dst = (const long long*)edges + NE;
        for (int i = lo + tid; i < hi; i += 256)
            atomicAdd(&h[(int)__builtin_nontemporal_load(&dst[i]) / BNODES], 1);
    } else {
        const int* dst = (const int*)edges + NE;
        for (int i = lo + tid; i < hi; i += 256)
            atomicAdd(&h[__builtin_nontemporal_load(&dst[i]) / BNODES], 1);
    }
    __syncthreads();
    for (int i = tid; i < 512; i += 256) H[blk * 512 + i] = h[i];
}

// A2a: wave-per-bucket exclusive scan over 256 block entries; bsum[b] = total
__global__ __launch_bounds__(256) void scan1_kernel(int* H, int* bsum) {
    int tid = threadIdx.x;
    int lane = tid & 63;
    int b = blockIdx.x * 4 + (tid >> 6);
    int v0 = H[(lane * 4 + 0) * 512 + b];
    int v1 = H[(lane * 4 + 1) * 512 + b];
    int v2 = H[(lane * 4 + 2) * 512 + b];
    int v3 = H[(lane * 4 + 3) * 512 + b];
    int t = v0 + v1 + v2 + v3;
    int sc = t;
#pragma unroll
    for (int off = 1; off < 64; off <<= 1) {
        int v = __shfl_up(sc, off, 64);
        if (lane >= off) sc += v;
    }
    int excl = sc - t;
    H[(lane * 4 + 0) * 512 + b] = excl;
    H[(lane * 4 + 1) * 512 + b] = excl + v0;
    H[(lane * 4 + 2) * 512 + b] = excl + v0 + v1;
    H[(lane * 4 + 3) * 512 + b] = excl + v0 + v1 + v2;
    if (lane == 63) bsum[b] = sc;
}

// A2b: exclusive prefix over 512 bucket totals -> bb[0..511], bb[512]
__global__ void bb2_kernel(const int* bsum, int* bb) {
    __shared__ int sc[512];
    int b = threadIdx.x;  // 512 threads
    int s = bsum[b];
    sc[b] = s;
    __syncthreads();
    for (int off = 1; off < 512; off <<= 1) {
        int v = (b >= off) ? sc[b - off] : 0;
        __syncthreads();
        sc[b] += v;
        __syncthreads();
    }
    bb[b] = sc[b] - s;
    if (b == 511) bb[512] = sc[511];
}

// A3: scatter packed records (dst_local<<17 | src); base = bb[b] + local prefix
__global__ __launch_bounds__(256) void scatter_kernel(const void* edges, const int* H,
                                                      const int* bb, u32* rec) {
    __shared__ int cur[512];
    int tid = threadIdx.x, blk = blockIdx.x;
    for (int i = tid; i < 512; i += 256) cur[i] = bb[i] + H[blk * 512 + i];
    __syncthreads();
    bool f = edges_are_i64(edges);
    int lo = blk * CHUNK, hi = lo + CHUNK;
    if (f) {
        const long long* e = (const long long*)edges;
        for (int i = lo + tid; i < hi; i += 256) {
            int d = (int)__builtin_nontemporal_load(&e[NE + i]);
            int s = (int)__builtin_nontemporal_load(&e[i]);
            int b = d / BNODES;
            int p = atomicAdd(&cur[b], 1);
            rec[p] = ((u32)(d - b * BNODES) << 17) | (u32)s;
        }
    } else {
        const int* e = (const int*)edges;
        for (int i = lo + tid; i < hi; i += 256) {
            int d = __builtin_nontemporal_load(&e[NE + i]);
            int s = __builtin_nontemporal_load(&e[i]);
            int b = d / BNODES;
            int p = atomicAdd(&cur[b], 1);
            rec[p] = ((u32)(d - b * BNODES) << 17) | (u32)s;
        }
    }
}

// B: per-bucket: LDS hist -> prefix -> cnt/offsets (no global atomics) -> csr scatter
__global__ __launch_bounds__(256) void bucket_csr_kernel(const u32* rec, const int* bb,
                                                         int* cnt, int* offsets, int* csr) {
    __shared__ int hcnt[200], hpre[200], hcur[200];
    int b = blockIdx.x, tid = threadIdx.x;
    int base = bb[b], total = bb[b + 1] - base;
    if (b == NB - 1 && tid < 8) csr[NE + tid] = 0;   // zero-pad tail for over-read
    for (int i = tid; i < BNODES; i += 256) hcnt[i] = 0;
    __syncthreads();
    for (int i = tid; i < total; i += 256)
        atomicAdd(&hcnt[__builtin_nontemporal_load(&rec[base + i]) >> 17], 1);
    __syncthreads();
    if (tid < 64) {  // wave 0: exclusive prefix over 196 counters (49 lanes x 4)
        int l = tid;
        int s0 = 0, s1 = 0, s2 = 0, s3 = 0;
        if (l < 49) {
            s0 = hcnt[l * 4]; s1 = hcnt[l * 4 + 1]; s2 = hcnt[l * 4 + 2]; s3 = hcnt[l * 4 + 3];
        }
        int t0 = s0, t1 = t0 + s1, t2 = t1 + s2, t3 = t2 + s3;
        int sc = t3;
#pragma unroll
        for (int off = 1; off < 64; off <<= 1) {
            int v = __shfl_up(sc, off, 64);
            if (l >= off) sc += v;
        }
        int lbase = sc - t3;
        if (l < 49) {
            hpre[l * 4] = lbase;      hpre[l * 4 + 1] = lbase + t0;
            hpre[l * 4 + 2] = lbase + t1; hpre[l * 4 + 3] = lbase + t2;
        }
    }
    __syncthreads();
    int node0 = b * BNODES;
    for (int i = tid; i < BNODES; i += 256) {
        int n = node0 + i;
        if (n < NN) { cnt[n] = hcnt[i]; offsets[n] = base + hpre[i]; }
    }
    for (int i = tid; i < BNODES; i += 256) hcur[i] = hpre[i];
    __syncthreads();
    for (int i = tid; i < total; i += 256) {
        u32 r = __builtin_nontemporal_load(&rec[base + i]);
        int p = atomicAdd(&hcur[r >> 17], 1);
        csr[base + p] = (int)(r & 0x1FFFFu);
    }
}

// FUSED agg+lin: block = 128 dst nodes, 512 threads (8 waves).
// Phase A: slot-gather mean-agg straight into LDS As (no aggb round-trip).
// Phase B: MFMA out = [agg || own-rows] x W + bias. Layer1 -> bf16 hb, layer2 -> f32 out.
__global__ __launch_bounds__(512) void fused_kernel(const u16* __restrict__ feat,
                                                    const int* __restrict__ csr,
                                                    const int* __restrict__ offsets,
                                                    const int* __restrict__ cnt,
                                                    const u16* __restrict__ Wst,
                                                    const float* __restrict__ bias,
                                                    float* outF, u16* outH, int relu) {
    __shared__ u16 As[128][136];   // +8 pad
    __shared__ u16 Ws[16384];      // one 128-K chunk: [16 kb][128 col][8 k]

    int tid = threadIdx.x;
    int lane = tid & 63;
    int w = tid >> 6;             // wave 0..7
    int slot = lane >> 4;         // node slot 0..3
    int c16 = lane & 15;          // 16B chunk within 256B row
    int nb = blockIdx.x * 128;
    int l15 = lane & 15, l4 = lane >> 4;

    // stage Ws chunk 0 (concurrent with Phase A's first gathers)
    for (int idx = tid; idx < 2048; idx += 512)
        *(float4*)&Ws[idx * 8] = *(const float4*)(Wst + idx * 8);

    // ---- Phase A: aggregate 128 nodes into As (4 iterations x 8 waves x 4 slots) ----
    for (int it = 0; it < 4; it++) {
        int nl = it * 32 + w * 4 + slot;
        int node = nb + nl;
        bool valid = node < NN;
        int beg = valid ? offsets[node] : 0;
        int deg = valid ? cnt[node] : 0;
        int md = deg;
        md = max(md, __shfl_xor(md, 16, 64));
        md = max(md, __shfl_xor(md, 32, 64));

        float acc[8];
#pragma unroll
        for (int q = 0; q < 8; q++) acc[q] = 0.f;

        for (int j = 0; j < md; j += 8) {
            int s[8];
#pragma unroll
            for (int k = 0; k < 8; k++) s[k] = __builtin_nontemporal_load(&csr[beg + j + k]);
            uint4 v[8];
#pragma unroll
            for (int k = 0; k < 8; k++) v[k] = *(const uint4*)(feat + (size_t)s[k] * 128 + c16 * 8);
#pragma unroll
            for (int k = 0; k < 8; k++) {
                float m = (j + k < deg) ? 1.0f : 0.0f;
                acc[0] = fmaf(m, __uint_as_float(v[k].x << 16), acc[0]);
                acc[1] = fmaf(m, __uint_as_float(v[k].x & 0xffff0000u), acc[1]);
                acc[2] = fmaf(m, __uint_as_float(v[k].y << 16), acc[2]);
                acc[3] = fmaf(m, __uint_as_float(v[k].y & 0xffff0000u), acc[3]);
                acc[4] = fmaf(m, __uint_as_float(v[k].z << 16), acc[4]);
                acc[5] = fmaf(m, __uint_as_float(v[k].z & 0xffff0000u), acc[5]);
                acc[6] = fmaf(m, __uint_as_float(v[k].w << 16), acc[6]);
                acc[7] = fmaf(m, __uint_as_float(v[k].w & 0xffff0000u), acc[7]);
            }
        }
        float inv = (deg > 0) ? 1.0f / (float)deg : 0.0f;
        uint4 pk;
        pk.x = (u32)f2bf(acc[0] * inv) | ((u32)f2bf(acc[1] * inv) << 16);
        pk.y = (u32)f2bf(acc[2] * inv) | ((u32)f2bf(acc[3] * inv) << 16);
        pk.z = (u32)f2bf(acc[4] * inv) | ((u32)f2bf(acc[5] * inv) << 16);
        pk.w = (u32)f2bf(acc[6] * inv) | ((u32)f2bf(acc[7] * inv) << 16);
        *(uint4*)&As[nl][c16 * 8] = pk;
    }
    __syncthreads();

    // ---- Phase B: MFMA. 8 waves: wr = w>>2 (2 row-halves), wc = w&3 (4 col-quarters) ----
    int wr = w >> 2, wc = w & 3;
    f32x4 acc2[4][2];
#pragma unroll
    for (int i = 0; i < 4; i++)
#pragma unroll
        for (int j = 0; j < 2; j++) acc2[i][j] = (f32x4){0.f, 0.f, 0.f, 0.f};

    // chunk 0: A = agg (already in As), Ws chunk 0 (already staged)
#pragma unroll
    for (int kk = 0; kk < 4; kk++) {
        frag a[4], bfr[2];
#pragma unroll
        for (int i = 0; i < 4; i++)
            a[i] = *(const frag*)&As[wr * 64 + i * 16 + l15][kk * 32 + l4 * 8];
#pragma unroll
        for (int j = 0; j < 2; j++)
            bfr[j] = *(const frag*)&Ws[((kk * 4 + l4) * 128 + wc * 32 + j * 16 + l15) * 8];
#pragma unroll
        for (int i = 0; i < 4; i++)
#pragma unroll
            for (int j = 0; j < 2; j++)
                acc2[i][j] = __builtin_amdgcn_mfma_f32_16x16x32_bf16(a[i], bfr[j], acc2[i][j], 0, 0, 0);
    }
    __syncthreads();

    // restage: As = own feature rows, Ws = chunk 1
    for (int idx = tid; idx < 128 * 16; idx += 512) {
        int row = idx >> 4, c = idx & 15;
        float4 v = make_float4(0.f, 0.f, 0.f, 0.f);
        if (nb + row < NN)
            v = *(const float4*)(feat + (size_t)(nb + row) * 128 + c * 8);
        *(float4*)&As[row][c * 8] = v;
    }
    for (int idx = tid; idx < 2048; idx += 512)
        *(float4*)&Ws[idx * 8] = *(const float4*)(Wst + 16384 + idx * 8);
    __syncthreads();

    // chunk 1
#pragma unroll
    for (int kk = 0; kk < 4; kk++) {
        frag a[4], bfr[2];
#pragma unroll
        for (int i = 0; i < 4; i++)
            a[i] = *(const frag*)&As[wr * 64 + i * 16 + l15][kk * 32 + l4 * 8];
#pragma unroll
        for (int j = 0; j < 2; j++)
            bfr[j] = *(const frag*)&Ws[((kk * 4 + l4) * 128 + wc * 32 + j * 16 + l15) * 8];
#pragma unroll
        for (int i = 0; i < 4; i++)
#pragma unroll
            for (int j = 0; j < 2; j++)
                acc2[i][j] = __builtin_amdgcn_mfma_f32_16x16x32_bf16(a[i], bfr[j], acc2[i][j], 0, 0, 0);
    }

    // epilogue: C/D layout col = lane&15, row = (lane>>4)*4 + reg
#pragma unroll
    for (int j = 0; j < 2; j++) {
        int col = wc * 32 + j * 16 + l15;
        float bv = bias[col];
#pragma unroll
        for (int i = 0; i < 4; i++) {
#pragma unroll
            for (int r = 0; r < 4; r++) {
                int node = nb + wr * 64 + i * 16 + l4 * 4 + r;
                if (node >= NN) continue;
                float v = acc2[i][j][r] + bv;
                if (relu) {
                    v = fmaxf(v, 0.f);
                    outH[(size_t)node * 128 + col] = f2bf(v);
                } else {
                    outF[(size_t)node * 128 + col] = v;
                }
            }
        }
    }
}

extern "C" void kernel_launch(void* const* d_in, const int* in_sizes, int n_in,
                              void* d_out, int out_size, void* d_ws, size_t ws_size,
                              hipStream_t stream) {
    const float* x    = (const float*)d_in[0];
    const void* edges = d_in[1];
    const float* Wl1  = (const float*)d_in[2];
    const float* Wr1  = (const float*)d_in[3];
    const float* b1   = (const float*)d_in[4];
    const float* Wl2  = (const float*)d_in[5];
    const float* Wr2  = (const float*)d_in[6];
    const float* b2   = (const float*)d_in[7];
    float* out = (float*)d_out;

    char* ws = (char*)d_ws;
    int* cnt     = (int*)(ws + OFF_CNT);
    int* offsets = (int*)(ws + OFF_OFFS);
    int* bb      = (int*)(ws + OFF_BB);
    int* bsum    = (int*)(ws + OFF_BSUM);
    int* H       = (int*)(ws + OFF_H);
    int* csr     = (int*)(ws + OFF_CSR);
    u16* Wst1    = (u16*)(ws + OFF_WT1);
    u16* Wst2    = (u16*)(ws + OFF_WT2);
    u16* xb      = (u16*)(ws + OFF_XB);
    u16* hb      = (u16*)(ws + OFF_HB);
    u32* rec     = (u32*)(ws + OFF_REC);   // overlaps hb tail; dead before fused1

    // build + prep (cvt/wtprep folded into hist)
    hist_kernel<<<NBLKA, 256, 0, stream>>>(edges, H, x, xb, Wl1, Wr1, Wl2, Wr2, Wst1, Wst2);
    scan1_kernel<<<128, 256, 0, stream>>>(H, bsum);
    bb2_kernel<<<1, 512, 0, stream>>>(bsum, bb);
    scatter_kernel<<<NBLKA, 256, 0, stream>>>(edges, H, bb, rec);
    bucket_csr_kernel<<<NB, 256, 0, stream>>>(rec, bb, cnt, offsets, csr);

    int fgrid = (NN + 127) / 128;  // 782

    // layer 1: hb = relu([agg(xb) || xb] @ W1 + b1), bf16
    fused_kernel<<<fgrid, 512, 0, stream>>>(xb, csr, offsets, cnt, Wst1, b1, nullptr, hb, 1);
    // layer 2: out = [agg(hb) || hb] @ W2 + b2, f32
    fused_kernel<<<fgrid, 512, 0, stream>>>(hb, csr, offsets, cnt, Wst2, b2, out, nullptr, 0);
}